// Round 5
// baseline (61.086 us; speedup 1.0000x reference)
//
#include <hip/hip_runtime.h>
#include <math.h>

// TensoIR physical rendering: N points x L lights -> 4 (N,3) outputs
// (rgb, wo_indir, wo_vis, indir), each linear->sRGB'd after the light sum.
//
// R5 changes vs R4 (waves spend ~95% of life waiting; block setup is pure
// overhead):
//  - prep kernel packs normalized light table ONCE into d_ws (ld4 = dir+w,
//    env4 = rgb) -> main kernel reads it straight from L2 (16 KB, resident).
//  - main kernel: NO LDS, NO __syncthreads, no per-block staging/normalize.
//    Waves fully independent; light-table reads are dense coalesced float4.
//  - keeps R4 algebra (2 dot products/pair), stride-64 light mapping,
//    full unroll.

#define PI_F     3.14159265358979323846f
#define FOURPI_F (4.0f * PI_F)

__device__ __forceinline__ float fast_rcp(float x)  { float r; asm("v_rcp_f32 %0, %1" : "=v"(r) : "v"(x)); return r; }
__device__ __forceinline__ float fast_rsq(float x)  { float r; asm("v_rsq_f32 %0, %1" : "=v"(r) : "v"(x)); return r; }
__device__ __forceinline__ float fast_exp2(float x) { float r; asm("v_exp_f32 %0, %1" : "=v"(r) : "v"(x)); return r; }
__device__ __forceinline__ float fast_log2(float x) { float r; asm("v_log_f32 %0, %1" : "=v"(r) : "v"(x)); return r; }

__device__ __forceinline__ float lin2srgb(float x) {
  float lin = 12.92f * x;
  float xe  = fmaxf(x, 1e-8f);
  float e   = 1.055f * fast_exp2(fast_log2(xe) * (1.0f / 2.4f)) - 0.055f;
  return (x <= 0.0031308f) ? lin : e;
}

__device__ __forceinline__ float clamp01(float x) { return fminf(fmaxf(x, 0.0f), 1.0f); }
__device__ __forceinline__ float clampe(float x)  { return fminf(fmaxf(x, 1e-6f), 1.0f); }

// ---- prep: pack normalized light dirs + weight, env rgbs into d_ws ----
__global__ void __launch_bounds__(256)
prep_lights(const float* __restrict__ light_dirs, const float* __restrict__ law,
            const float* __restrict__ env_rgbs, float4* __restrict__ ld_tbl,
            float4* __restrict__ env_tbl, int L) {
  int l = blockIdx.x * 256 + threadIdx.x;
  if (l >= L) return;
  float lx = light_dirs[3 * l + 0];
  float ly = light_dirs[3 * l + 1];
  float lz = light_dirs[3 * l + 2];
  float inv = fast_rsq(fmaxf(lx * lx + ly * ly + lz * lz, 1e-12f));
  ld_tbl[l]  = make_float4(lx * inv, ly * inv, lz * inv, law[l]);
  env_tbl[l] = make_float4(env_rgbs[3 * l + 0], env_rgbs[3 * l + 1],
                           env_rgbs[3 * l + 2], 0.0f);
}

// LC = compile-time light count (0 => runtime L)
template <int LC>
__global__ void __launch_bounds__(256)
tensoir_render(const float* __restrict__ viewdirs,  // (N,3)
               const float* __restrict__ albedo,    // (N,3)
               const float* __restrict__ roughness, // (N,1)
               const float* __restrict__ fresnel,   // (N,3)
               const float* __restrict__ normal,    // (N,3)
               const float4* __restrict__ ld_tbl,   // (L,) dir+w, prepped
               const float4* __restrict__ env_tbl,  // (L,) rgb,  prepped
               const float* __restrict__ visibility,// (N,L,1)
               const float* __restrict__ indirect,  // (N,L,3)
               float* __restrict__ out,             // 4*N*3
               int N, int Lrt) {
  const int L = LC ? LC : Lrt;
  const int tid = threadIdx.x;
  const int lane = tid & 63;
  int n = blockIdx.x * 4 + (tid >> 6);
  if (n >= N) n = N - 1;  // tail: duplicate work, identical writes

  float vx = -viewdirs[3 * n + 0], vy = -viewdirs[3 * n + 1], vz = -viewdirs[3 * n + 2];
  float nx = normal[3 * n + 0], ny = normal[3 * n + 1], nz = normal[3 * n + 2];
  float rough0 = roughness[n];
  const float fr = fresnel[3 * n + 0], fg = fresnel[3 * n + 1], fb = fresnel[3 * n + 2];
  float ar0 = albedo[3 * n + 0], ag0 = albedo[3 * n + 1], ab0 = albedo[3 * n + 2];

  {
    float inv = fast_rsq(fmaxf(vx * vx + vy * vy + vz * vz, 1e-12f));
    vx *= inv; vy *= inv; vz *= inv;
  }
  {
    float inv = fast_rsq(fmaxf(nx * nx + ny * ny + nz * nz, 1e-12f));
    nx *= inv; ny *= inv; nz *= inv;
  }
  const float rough  = clamp01(rough0 * 0.9f + 0.09f);
  const float alpha  = rough * rough;
  const float alpha2 = alpha * alpha;
  const float a2m1   = alpha2 - 1.0f;
  const float kk     = (alpha + 2.0f * rough + 1.0f) * 0.125f;
  const float onemk  = 1.0f - kk;

  const float omfr = 1.0f - fr, omfg = 1.0f - fg, omfb = 1.0f - fb;
  const float ar = clamp01(ar0) * (1.0f / PI_F);
  const float ag = clamp01(ag0) * (1.0f / PI_F);
  const float ab = clamp01(ab0) * (1.0f / PI_F);

  const float NoV0 = vx * nx + vy * ny + vz * nz;
  const float sgn  = (NoV0 >= 0.0f) ? 1.0f : -1.0f;
  const float aNoV = fabsf(NoV0);              // Nf . V (exact)
  const float NoV  = clampe(aNoV);
  const float nom1 = NoV * onemk + kk;
  const float c1   = FOURPI_F * nom1;          // hoisted constant factor

  // 9 accumulators: {wo_indir, wo_vis, indir} x {r,g,b}; rgb = wo_indir+indir.
  float s1r = 0, s1g = 0, s1b = 0;
  float s2r = 0, s2g = 0, s2b = 0;
  float s3r = 0, s3g = 0, s3b = 0;

  const float* visrow = visibility + (size_t)n * L;
  const float* indrow = indirect + (size_t)n * L * 3;

  auto body = [&](int i) {
    const float4 ld = ld_tbl[i];
    const float4 ev = env_tbl[i];
    const float visv = visrow[i];
    const float ir = indrow[3 * i + 0];
    const float ig = indrow[3 * i + 1];
    const float ib = indrow[3 * i + 2];

    // two dot products only (|L|=|V|=|N|=1 identities)
    const float cos0 = ld.x * nx + ld.y * ny + ld.z * nz;   // L . N
    const float LoV  = ld.x * vx + ld.y * vy + ld.z * vz;   // L . V

    const float cosine = fmaxf(cos0, 0.0f);
    const bool  mask   = cos0 > 1e-6f;
    const float w      = cosine * ld.w;

    const float NoL0 = sgn * cos0;                           // Nf . L
    const float NoL  = clampe(NoL0);

    const float h2   = fmaf(2.0f, LoV, 2.0f);                // |L+V|^2
    const float hinv = fast_rsq(fmaxf(h2, 1e-12f));
    const float VoH  = clampe((1.0f + LoV) * hinv);          // V.(L+V)/|h|
    const float NoH  = clampe((NoL0 + aNoV) * hinv);         // Nf.(L+V)/|h|

    const float FMi = (-5.55473f * VoH - 6.98316f) * VoH;
    const float p2  = fast_exp2(FMi);
    const float nom0 = fmaf(NoH * NoH, a2m1, 1.0f);
    const float nom2 = fmaf(NoL, onemk, kk);
    const float nom  = fminf(fmaxf(c1 * (nom0 * nom0) * nom2, 1e-6f), FOURPI_F);
    const float ss   = alpha2 * fast_rcp(nom);

    const float br = fmaf(fmaf(omfr, p2, fr), ss, ar);
    const float bg = fmaf(fmaf(omfg, p2, fg), ss, ag);
    const float bb = fmaf(fmaf(omfb, p2, fb), ss, ab);

    const float vism = mask ? visv : 0.0f;
    const float irm  = mask ? ir : 0.0f;
    const float igm  = mask ? ig : 0.0f;
    const float ibm  = mask ? ib : 0.0f;

    const float twr = br * w, twg = bg * w, twb = bb * w;

    s1r = fmaf(twr, vism * ev.x, s1r);
    s1g = fmaf(twg, vism * ev.y, s1g);
    s1b = fmaf(twb, vism * ev.z, s1b);
    s2r = fmaf(twr, ev.x, s2r);
    s2g = fmaf(twg, ev.y, s2g);
    s2b = fmaf(twb, ev.z, s2b);
    s3r = fmaf(twr, irm, s3r);
    s3g = fmaf(twg, igm, s3g);
    s3b = fmaf(twb, ibm, s3b);
  };

  if (LC) {
    constexpr int NITER = LC ? LC / 64 : 1;
#pragma unroll
    for (int j = 0; j < NITER; ++j) body(lane + 64 * j);
  } else {
    for (int i = lane; i < L; i += 64) body(i);
  }

#define WAVE_RED(v)                 \
  do {                              \
    v += __shfl_xor(v, 32);         \
    v += __shfl_xor(v, 16);         \
    v += __shfl_xor(v, 8);          \
    v += __shfl_xor(v, 4);          \
    v += __shfl_xor(v, 2);          \
    v += __shfl_xor(v, 1);          \
  } while (0)
  WAVE_RED(s1r); WAVE_RED(s1g); WAVE_RED(s1b);
  WAVE_RED(s2r); WAVE_RED(s2g); WAVE_RED(s2b);
  WAVE_RED(s3r); WAVE_RED(s3g); WAVE_RED(s3b);
#undef WAVE_RED

  if (lane == 0) {
    const size_t stride = (size_t)3 * N;
    float* o0 = out + 3 * (size_t)n;             // rgb
    float* o1 = o0 + stride;                     // wo_indir
    float* o2 = o1 + stride;                     // wo_vis
    float* o3 = o2 + stride;                     // indir
    o0[0] = lin2srgb(clamp01(s1r + s3r));
    o0[1] = lin2srgb(clamp01(s1g + s3g));
    o0[2] = lin2srgb(clamp01(s1b + s3b));
    o1[0] = lin2srgb(s1r); o1[1] = lin2srgb(s1g); o1[2] = lin2srgb(s1b);
    o2[0] = lin2srgb(s2r); o2[1] = lin2srgb(s2g); o2[2] = lin2srgb(s2b);
    o3[0] = lin2srgb(s3r); o3[1] = lin2srgb(s3g); o3[2] = lin2srgb(s3b);
  }
}

extern "C" void kernel_launch(void* const* d_in, const int* in_sizes, int n_in,
                              void* d_out, int out_size, void* d_ws, size_t ws_size,
                              hipStream_t stream) {
  const float* viewdirs   = (const float*)d_in[0];
  const float* albedo     = (const float*)d_in[1];
  const float* roughness  = (const float*)d_in[2];
  const float* fresnel    = (const float*)d_in[3];
  const float* normal     = (const float*)d_in[4];
  const float* light_dirs = (const float*)d_in[5];
  const float* law        = (const float*)d_in[6];
  const float* env_rgbs   = (const float*)d_in[7];
  const float* visibility = (const float*)d_in[8];
  const float* indirect   = (const float*)d_in[9];
  float* out = (float*)d_out;

  const int N = in_sizes[0] / 3;
  const int L = in_sizes[6];   // light_area_weight is (L,)

  float4* ld_tbl  = (float4*)d_ws;           // L float4
  float4* env_tbl = ld_tbl + L;              // L float4

  hipLaunchKernelGGL(prep_lights, dim3((L + 255) / 256), dim3(256), 0, stream,
                     light_dirs, law, env_rgbs, ld_tbl, env_tbl, L);

  dim3 block(256);
  dim3 grid((N + 3) / 4);  // 4 points (waves) per block

  if (L == 512) {
    hipLaunchKernelGGL(tensoir_render<512>, grid, block, 0, stream,
                       viewdirs, albedo, roughness, fresnel, normal,
                       ld_tbl, env_tbl, visibility, indirect,
                       out, N, L);
  } else {
    hipLaunchKernelGGL(tensoir_render<0>, grid, block, 0, stream,
                       viewdirs, albedo, roughness, fresnel, normal,
                       ld_tbl, env_tbl, visibility, indirect,
                       out, N, L);
  }
}

// Round 6
// 53.876 us; speedup vs baseline: 1.1338x; 1.1338x over previous
//
#include <hip/hip_runtime.h>
#include <math.h>

// TensoIR physical rendering: N points x L lights -> 4 (N,3) outputs
// (rgb, wo_indir, wo_vis, indir), each linear->sRGB'd after the light sum.
//
// R6 = R4 structure (best: 52.7us; LDS staging is load-bearing per R5's
// regression) + explicit MLP:
//  - ALL 16 stream loads per point hoisted before compute, interleaved by
//    iteration (vis[j], ind[j]) so body j's s_waitcnt covers only its loads.
//  - ind loaded as 12B float3 (global_load_dwordx3): dense 768B/wave-instr,
//    stride-64 lane mapping kept (R3's consecutive-light float4 regressed).
//  - __launch_bounds__(256,4): cap VGPR at 128 -> >=16 waves/CU.

#define PI_F     3.14159265358979323846f
#define FOURPI_F (4.0f * PI_F)
#define MAXL     512

struct f3 { float x, y, z; };   // 12B, 4B-aligned -> dwordx3

__device__ __forceinline__ float fast_rcp(float x)  { float r; asm("v_rcp_f32 %0, %1" : "=v"(r) : "v"(x)); return r; }
__device__ __forceinline__ float fast_rsq(float x)  { float r; asm("v_rsq_f32 %0, %1" : "=v"(r) : "v"(x)); return r; }
__device__ __forceinline__ float fast_exp2(float x) { float r; asm("v_exp_f32 %0, %1" : "=v"(r) : "v"(x)); return r; }
__device__ __forceinline__ float fast_log2(float x) { float r; asm("v_log_f32 %0, %1" : "=v"(r) : "v"(x)); return r; }

__device__ __forceinline__ float lin2srgb(float x) {
  float lin = 12.92f * x;
  float xe  = fmaxf(x, 1e-8f);
  float e   = 1.055f * fast_exp2(fast_log2(xe) * (1.0f / 2.4f)) - 0.055f;
  return (x <= 0.0031308f) ? lin : e;
}

__device__ __forceinline__ float clamp01(float x) { return fminf(fmaxf(x, 0.0f), 1.0f); }
__device__ __forceinline__ float clampe(float x)  { return fminf(fmaxf(x, 1e-6f), 1.0f); }

// LC = compile-time light count (0 => runtime L)
template <int LC>
__global__ void __launch_bounds__(256, 4)
tensoir_render(const float* __restrict__ viewdirs,  // (N,3)
               const float* __restrict__ albedo,    // (N,3)
               const float* __restrict__ roughness, // (N,1)
               const float* __restrict__ fresnel,   // (N,3)
               const float* __restrict__ normal,    // (N,3)
               const float* __restrict__ light_dirs,// (L,3)
               const float* __restrict__ law,       // (L,)
               const float* __restrict__ env_rgbs,  // (L,3)
               const float* __restrict__ visibility,// (N,L,1)
               const float* __restrict__ indirect,  // (N,L,3)
               float* __restrict__ out,             // 4*N*3
               int N, int Lrt) {
  __shared__ float4 s_ld[MAXL];   // normalized light dir xyz, area weight
  __shared__ float4 s_env[MAXL];  // env rgb, pad

  const int L = LC ? LC : Lrt;
  const int tid = threadIdx.x;
  const int lane = tid & 63;
  int n = blockIdx.x * 4 + (tid >> 6);
  if (n >= N) n = N - 1;  // tail: duplicate work, identical writes

  // per-point scalar loads issued before staging (independent)
  float vx = -viewdirs[3 * n + 0], vy = -viewdirs[3 * n + 1], vz = -viewdirs[3 * n + 2];
  float nx = normal[3 * n + 0], ny = normal[3 * n + 1], nz = normal[3 * n + 2];
  float rough0 = roughness[n];
  const float fr = fresnel[3 * n + 0], fg = fresnel[3 * n + 1], fb = fresnel[3 * n + 2];
  float ar0 = albedo[3 * n + 0], ag0 = albedo[3 * n + 1], ab0 = albedo[3 * n + 2];

  // stage light table (per block)
  for (int l = tid; l < L && l < MAXL; l += 256) {
    float lx = light_dirs[3 * l + 0];
    float ly = light_dirs[3 * l + 1];
    float lz = light_dirs[3 * l + 2];
    float inv = fast_rsq(fmaxf(lx * lx + ly * ly + lz * lz, 1e-12f));
    s_ld[l]  = make_float4(lx * inv, ly * inv, lz * inv, law[l]);
    s_env[l] = make_float4(env_rgbs[3 * l + 0], env_rgbs[3 * l + 1],
                           env_rgbs[3 * l + 2], 0.0f);
  }
  __syncthreads();

  // ---- per-point (wave-uniform) setup ----
  {
    float inv = fast_rsq(fmaxf(vx * vx + vy * vy + vz * vz, 1e-12f));
    vx *= inv; vy *= inv; vz *= inv;
  }
  {
    float inv = fast_rsq(fmaxf(nx * nx + ny * ny + nz * nz, 1e-12f));
    nx *= inv; ny *= inv; nz *= inv;
  }
  const float rough  = clamp01(rough0 * 0.9f + 0.09f);
  const float alpha  = rough * rough;
  const float alpha2 = alpha * alpha;
  const float a2m1   = alpha2 - 1.0f;
  const float kk     = (alpha + 2.0f * rough + 1.0f) * 0.125f;
  const float onemk  = 1.0f - kk;

  const float omfr = 1.0f - fr, omfg = 1.0f - fg, omfb = 1.0f - fb;
  const float ar = clamp01(ar0) * (1.0f / PI_F);
  const float ag = clamp01(ag0) * (1.0f / PI_F);
  const float ab = clamp01(ab0) * (1.0f / PI_F);

  const float NoV0 = vx * nx + vy * ny + vz * nz;
  const float sgn  = (NoV0 >= 0.0f) ? 1.0f : -1.0f;
  const float aNoV = fabsf(NoV0);              // Nf . V (exact)
  const float NoV  = clampe(aNoV);
  const float nom1 = NoV * onemk + kk;
  const float c1   = FOURPI_F * nom1;          // hoisted constant factor

  // 9 accumulators: {wo_indir, wo_vis, indir} x {r,g,b}; rgb = wo_indir+indir.
  float s1r = 0, s1g = 0, s1b = 0;
  float s2r = 0, s2g = 0, s2b = 0;
  float s3r = 0, s3g = 0, s3b = 0;

  const float* visrow = visibility + (size_t)n * L;
  const float* indrow = indirect + (size_t)n * L * 3;

  auto body = [&](int i, float visv, float ir, float ig, float ib) {
    const float4 ld = s_ld[i];
    const float4 ev = s_env[i];

    // two dot products only (|L|=|V|=|N|=1 identities)
    const float cos0 = ld.x * nx + ld.y * ny + ld.z * nz;   // L . N
    const float LoV  = ld.x * vx + ld.y * vy + ld.z * vz;   // L . V

    const float cosine = fmaxf(cos0, 0.0f);
    const bool  mask   = cos0 > 1e-6f;
    const float w      = cosine * ld.w;

    const float NoL0 = sgn * cos0;                           // Nf . L
    const float NoL  = clampe(NoL0);

    const float h2   = fmaf(2.0f, LoV, 2.0f);                // |L+V|^2
    const float hinv = fast_rsq(fmaxf(h2, 1e-12f));
    const float VoH  = clampe((1.0f + LoV) * hinv);          // V.(L+V)/|h|
    const float NoH  = clampe((NoL0 + aNoV) * hinv);         // Nf.(L+V)/|h|

    const float FMi = (-5.55473f * VoH - 6.98316f) * VoH;
    const float p2  = fast_exp2(FMi);
    const float nom0 = fmaf(NoH * NoH, a2m1, 1.0f);
    const float nom2 = fmaf(NoL, onemk, kk);
    const float nom  = fminf(fmaxf(c1 * (nom0 * nom0) * nom2, 1e-6f), FOURPI_F);
    const float ss   = alpha2 * fast_rcp(nom);

    const float br = fmaf(fmaf(omfr, p2, fr), ss, ar);
    const float bg = fmaf(fmaf(omfg, p2, fg), ss, ag);
    const float bb = fmaf(fmaf(omfb, p2, fb), ss, ab);

    const float vism = mask ? visv : 0.0f;
    const float irm  = mask ? ir : 0.0f;
    const float igm  = mask ? ig : 0.0f;
    const float ibm  = mask ? ib : 0.0f;

    const float twr = br * w, twg = bg * w, twb = bb * w;

    s1r = fmaf(twr, vism * ev.x, s1r);
    s1g = fmaf(twg, vism * ev.y, s1g);
    s1b = fmaf(twb, vism * ev.z, s1b);
    s2r = fmaf(twr, ev.x, s2r);
    s2g = fmaf(twg, ev.y, s2g);
    s2b = fmaf(twb, ev.z, s2b);
    s3r = fmaf(twr, irm, s3r);
    s3g = fmaf(twg, igm, s3g);
    s3b = fmaf(twb, ibm, s3b);
  };

  if (LC) {
    constexpr int NITER = LC ? LC / 64 : 1;
    const f3* ind3 = (const f3*)indrow;

    // ---- hoist ALL stream loads, interleaved by iteration ----
    float va[NITER];
    f3    ia[NITER];
#pragma unroll
    for (int j = 0; j < NITER; ++j) {
      va[j] = visrow[lane + 64 * j];
      ia[j] = ind3[lane + 64 * j];
    }
#pragma unroll
    for (int j = 0; j < NITER; ++j)
      body(lane + 64 * j, va[j], ia[j].x, ia[j].y, ia[j].z);
  } else {
    for (int i = lane; i < L; i += 64)
      body(i, visrow[i], indrow[3 * i + 0], indrow[3 * i + 1], indrow[3 * i + 2]);
  }

#define WAVE_RED(v)                 \
  do {                              \
    v += __shfl_xor(v, 32);         \
    v += __shfl_xor(v, 16);         \
    v += __shfl_xor(v, 8);          \
    v += __shfl_xor(v, 4);          \
    v += __shfl_xor(v, 2);          \
    v += __shfl_xor(v, 1);          \
  } while (0)
  WAVE_RED(s1r); WAVE_RED(s1g); WAVE_RED(s1b);
  WAVE_RED(s2r); WAVE_RED(s2g); WAVE_RED(s2b);
  WAVE_RED(s3r); WAVE_RED(s3g); WAVE_RED(s3b);
#undef WAVE_RED

  if (lane == 0) {
    const size_t stride = (size_t)3 * N;
    float* o0 = out + 3 * (size_t)n;             // rgb
    float* o1 = o0 + stride;                     // wo_indir
    float* o2 = o1 + stride;                     // wo_vis
    float* o3 = o2 + stride;                     // indir
    o0[0] = lin2srgb(clamp01(s1r + s3r));
    o0[1] = lin2srgb(clamp01(s1g + s3g));
    o0[2] = lin2srgb(clamp01(s1b + s3b));
    o1[0] = lin2srgb(s1r); o1[1] = lin2srgb(s1g); o1[2] = lin2srgb(s1b);
    o2[0] = lin2srgb(s2r); o2[1] = lin2srgb(s2g); o2[2] = lin2srgb(s2b);
    o3[0] = lin2srgb(s3r); o3[1] = lin2srgb(s3g); o3[2] = lin2srgb(s3b);
  }
}

extern "C" void kernel_launch(void* const* d_in, const int* in_sizes, int n_in,
                              void* d_out, int out_size, void* d_ws, size_t ws_size,
                              hipStream_t stream) {
  const float* viewdirs   = (const float*)d_in[0];
  const float* albedo     = (const float*)d_in[1];
  const float* roughness  = (const float*)d_in[2];
  const float* fresnel    = (const float*)d_in[3];
  const float* normal     = (const float*)d_in[4];
  const float* light_dirs = (const float*)d_in[5];
  const float* law        = (const float*)d_in[6];
  const float* env_rgbs   = (const float*)d_in[7];
  const float* visibility = (const float*)d_in[8];
  const float* indirect   = (const float*)d_in[9];
  float* out = (float*)d_out;

  const int N = in_sizes[0] / 3;
  const int L = in_sizes[6];   // light_area_weight is (L,)

  dim3 block(256);
  dim3 grid((N + 3) / 4);  // 4 points (waves) per block

  if (L == 512) {
    hipLaunchKernelGGL(tensoir_render<512>, grid, block, 0, stream,
                       viewdirs, albedo, roughness, fresnel, normal,
                       light_dirs, law, env_rgbs, visibility, indirect,
                       out, N, L);
  } else {
    hipLaunchKernelGGL(tensoir_render<0>, grid, block, 0, stream,
                       viewdirs, albedo, roughness, fresnel, normal,
                       light_dirs, law, env_rgbs, visibility, indirect,
                       out, N, L);
  }
}